// Round 7
// baseline (191.565 us; speedup 1.0000x reference)
//
#include <hip/hip_runtime.h>

// CausalSelfAttention: B=4, S=2048, D=1024, H=16, HS=64
// bf16 MFMA everywhere, fp32 accumulate.
// GEMMs: 256x128 tile, 8 waves, k-split half-tile pipeline (counted vmcnt).
// attn v6: 32x32 MFMA swapped operands, ONE 32-row group per wave (grid 1024,
// 4 blocks/CU), CU-balanced qt permutation, pre-scaled Q (exp2 domain).

typedef unsigned short u16;
typedef short bf16x8 __attribute__((ext_vector_type(8)));
typedef unsigned short u16x8 __attribute__((ext_vector_type(8)));
typedef float f32x4 __attribute__((ext_vector_type(4)));
typedef float f32x16 __attribute__((ext_vector_type(16)));

#define S_LEN 2048
#define DMODEL 1024
#define NHEAD 16
#define MROWS 8192  // B*S

// 0.25 (1/sqrt(H)) * log2(e)
#define SCALE_LOG2E 0.36067376022224085f
#define DEFER_THR 8.0f

__device__ __forceinline__ u16 f2bf(float f) {
  union { float f; unsigned u; } c; c.f = f;
  unsigned u = c.u;
  u += 0x7fffu + ((u >> 16) & 1u);  // RNE
  return (u16)(u >> 16);
}

__device__ __forceinline__ float exp2_fast(float x) {
  float r; asm("v_exp_f32 %0, %1" : "=v"(r) : "v"(x)); return r;
}

__device__ __forceinline__ unsigned cvtpk_bf16(float a, float b) {
  unsigned r;
  asm("v_cvt_pk_bf16_f32 %0, %1, %2" : "=v"(r) : "v"(a), "v"(b));
  return r;
}

// v_permlane32_swap_b32: a' = {a_lo, b_lo}, b' = {a_hi, b_hi}
__device__ __forceinline__ void plswap(unsigned& a, unsigned& b) {
  asm("v_permlane32_swap_b32 %0, %1" : "+v"(a), "+v"(b));
}

__device__ __forceinline__ f32x4 mfma16(bf16x8 a, bf16x8 b, f32x4 c) {
  return __builtin_amdgcn_mfma_f32_16x16x32_bf16(a, b, c, 0, 0, 0);
}

__device__ __forceinline__ f32x16 mfma32(bf16x8 a, bf16x8 b, f32x16 c) {
  return __builtin_amdgcn_mfma_f32_32x32x16_bf16(a, b, c, 0, 0, 0);
}

__device__ __forceinline__ void gload_lds16(const void* g, void* l) {
  __builtin_amdgcn_global_load_lds((__attribute__((address_space(1))) void*)g,
                                   (__attribute__((address_space(3))) void*)l,
                                   16, 0, 0);
}

// ---------------- conversion kernels ----------------
__global__ void k_f32_to_bf16(const float* __restrict__ in, u16* __restrict__ out, int n) {
  int i = (blockIdx.x * 256 + threadIdx.x) * 4;
  if (i < n) {
    float4 v = *reinterpret_cast<const float4*>(in + i);
    ushort4 o;
    o.x = f2bf(v.x); o.y = f2bf(v.y); o.z = f2bf(v.z); o.w = f2bf(v.w);
    *reinterpret_cast<ushort4*>(out + i) = o;
  }
}

// w[K][N] fp32 -> wt[N][K] bf16
__global__ void k_transpose_to_bf16(const float* __restrict__ in, u16* __restrict__ out,
                                    int K, int N) {
  __shared__ float t[32][33];
  int n0 = blockIdx.x * 32, k0 = blockIdx.y * 32;
  int tx = threadIdx.x & 31, ty = threadIdx.x >> 5;  // 32 x 8
#pragma unroll
  for (int i = 0; i < 32; i += 8)
    t[ty + i][tx] = in[(size_t)(k0 + ty + i) * N + n0 + tx];
  __syncthreads();
#pragma unroll
  for (int i = 0; i < 32; i += 8)
    out[(size_t)(n0 + ty + i) * K + k0 + tx] = f2bf(t[tx][ty + i]);
}

// ---------------- GEMM v2: C[M][N] = A[M][K] * Bt[N][K]^T + bias ----------------
// 256x128 tile, 512 threads (8 waves: 4 wr x 2 wc), BK=64 as two k-halves.
// MODE 1: fp32 out.  MODE 2: qkv-split (col<1024 -> Q pre-scaled by SCALE_LOG2E;
// col<2048 -> qk bf16; else V -> vt^T).
template <int MODE>
__global__ __launch_bounds__(512, 1) void k_gemm8(const u16* __restrict__ A,
                                                  const u16* __restrict__ Bt,
                                                  const float* __restrict__ bias,
                                                  u16* __restrict__ outb,
                                                  float* __restrict__ outf,
                                                  u16* __restrict__ vtout,
                                                  int N, int K) {
  __shared__ u16 As[2][2][256 * 32];  // [buf][khalf][row][32 k-elems], 64B rows
  __shared__ u16 Bs[2][2][128 * 32];

  const int tid = threadIdx.x;
  const int lane = tid & 63, wave = tid >> 6;
  const int wr = wave >> 1, wc = wave & 1;
  const int lr = lane & 15, lk = lane >> 4;
  const int m0 = blockIdx.x * 256, n0 = blockIdx.y * 128;
  const size_t Kb = (size_t)K * 2;  // row stride bytes

  const int csw = ((tid & 3) ^ ((tid >> 3) & 3)) * 16;
  const char* Asrc0 = (const char*)A + (size_t)(m0 + (tid >> 2)) * Kb + csw;
  const char* Asrc1 = Asrc0 + 128 * Kb;
  const char* Bsrc0 = (const char*)Bt + (size_t)(n0 + (tid >> 2)) * Kb + csw;

#define STAGE_KH(BUFX, KH, T)                                                  \
  {                                                                            \
    const size_t ko_ = (size_t)(T) * 128 + (KH) * 64;                          \
    gload_lds16(Asrc0 + ko_, &As[BUFX][KH][(size_t)tid * 8]);                  \
    gload_lds16(Asrc1 + ko_, &As[BUFX][KH][((size_t)tid + 512) * 8]);          \
    gload_lds16(Bsrc0 + ko_, &Bs[BUFX][KH][(size_t)tid * 8]);                  \
  }

  f32x4 zero4 = {0.f, 0.f, 0.f, 0.f};
  f32x4 acc[4][4];
#pragma unroll
  for (int m = 0; m < 4; ++m)
#pragma unroll
    for (int n = 0; n < 4; ++n) acc[m][n] = zero4;

  const int slotsw = (lr >> 1) & 3;  // read-side swizzle: chunk = lk ^ slotsw

#define PHASE(BUFX, KH, T, DOSTAGE, VMZERO)                                    \
  {                                                                            \
    if (VMZERO) asm volatile("s_waitcnt vmcnt(0)" ::: "memory");               \
    else        asm volatile("s_waitcnt vmcnt(3)" ::: "memory");               \
    __builtin_amdgcn_s_barrier();                                              \
    __builtin_amdgcn_sched_barrier(0);                                         \
    bf16x8 af[4], bfr[4];                                                      \
    _Pragma("unroll") for (int m = 0; m < 4; ++m)                              \
        af[m] = *reinterpret_cast<const bf16x8*>(                              \
            &As[BUFX][KH][(wr * 64 + m * 16 + lr) * 32 + ((lk ^ slotsw) * 8)]);\
    _Pragma("unroll") for (int n = 0; n < 4; ++n)                              \
        bfr[n] = *reinterpret_cast<const bf16x8*>(                             \
            &Bs[BUFX][KH][(wc * 64 + n * 16 + lr) * 32 + ((lk ^ slotsw) * 8)]);\
    if (DOSTAGE) STAGE_KH((BUFX) ^ 1, KH, (T) + 1);                            \
    __builtin_amdgcn_sched_barrier(0);                                         \
    __builtin_amdgcn_s_setprio(1);                                             \
    _Pragma("unroll") for (int m = 0; m < 4; ++m)                              \
        _Pragma("unroll") for (int n = 0; n < 4; ++n)                          \
            acc[m][n] = mfma16(af[m], bfr[n], acc[m][n]);                      \
    __builtin_amdgcn_s_setprio(0);                                             \
  }

  const int nkt = K >> 6;  // 16
  STAGE_KH(0, 0, 0);
  STAGE_KH(0, 1, 0);

  for (int t = 0; t < nkt - 1; ++t) {
    const int buf = t & 1;
    PHASE(buf, 0, t, 1, 0);
    PHASE(buf, 1, t, 1, 0);
  }
  {
    const int buf = (nkt - 1) & 1;
    PHASE(buf, 0, nkt - 1, 0, 0);
    PHASE(buf, 1, nkt - 1, 0, 1);
  }
#undef PHASE
#undef STAGE_KH

  // epilogue
#pragma unroll
  for (int n = 0; n < 4; ++n) {
    int col = n0 + wc * 64 + n * 16 + lr;
    float bv = bias[col];
#pragma unroll
    for (int m = 0; m < 4; ++m) {
      int rowb = m0 + wr * 64 + m * 16 + lk * 4;
      if (MODE == 1) {
#pragma unroll
        for (int r = 0; r < 4; ++r)
          outf[(size_t)(rowb + r) * N + col] = acc[m][n][r] + bv;
      } else {
        if (col < 2048) {
          const float qs = (col < 1024) ? SCALE_LOG2E : 1.0f;  // pre-scale Q
#pragma unroll
          for (int r = 0; r < 4; ++r)
            outb[(size_t)(rowb + r) * 2048 + col] = f2bf((acc[m][n][r] + bv) * qs);
        } else {
          int hh = (col >> 6) & 15, dd = col & 63;
          int bb = rowb >> 11, ss = rowb & 2047;
          ushort4 o;
          o.x = f2bf(acc[m][n][0] + bv);
          o.y = f2bf(acc[m][n][1] + bv);
          o.z = f2bf(acc[m][n][2] + bv);
          o.w = f2bf(acc[m][n][3] + bv);
          *reinterpret_cast<ushort4*>(
              vtout + ((size_t)(bb * 16 + hh) * 64 + dd) * 2048 + ss) = o;
        }
      }
    }
  }
}

// ---------------- flash attention v6 (32x32 MFMA, 1 group/wave) ----------------
// grid 1024: bh = gid&63, tq = gid>>6 -> qt via CU-cohort-balancing permutation.
// Block 256 = 4 waves; wave owns 32 q rows (q0 = qt*128 + wave*32).
// S^T = K.Q^T with Q pre-scaled (exp2 domain); softmax lane-aligned (q=lane&31);
// P in-register via cvt_pk + permlane32_swap; O^T = V^T.P^T.
__global__ __launch_bounds__(256, 4) void k_attn6(const u16* __restrict__ qk,
                                                  const u16* __restrict__ vt,
                                                  u16* __restrict__ ao) {
  __shared__ u16 Ks[2][4096];   // [key 0..63][k 0..63], 128B rows, XOR-swizzled
  __shared__ u16 Vs[2][4096];   // [d 0..63][key 0..63], swizzled

  const int tid = threadIdx.x;
  const int lane = tid & 63, wave = tid >> 6;
  const int l31 = lane & 31, hi = lane >> 5;
  const int gid = blockIdx.x;
  const int bh = gid & 63;
  const int tq = gid >> 6;
  // permutation: cohorts {t, t+4, t+8, t+12} (same CU under 8-XCD round robin)
  // get qt sets summing to 30 -> uniform causal work per CU.
  const int g2 = tq >> 2, r2 = tq & 3;
  const int qt = (g2 == 0) ? 2 * r2
               : (g2 == 1) ? 15 - 2 * r2
               : (g2 == 2) ? 2 * r2 + 1
                           : 14 - 2 * r2;
  const int b = bh >> 4, h = bh & 15;

  const int q0 = qt * 128 + wave * 32;
  const int ktd = (q0 + 31) >> 6;        // wave's diagonal tile
  const int KTMAX = 2 * qt + 1;          // block-level last tile
  const int qrel = q0 + l31 - ktd * 64;  // mask: key_in_tile > qrel

  // Q fragments (B-operand): lane holds Q[q = l31][k = ks*16 + hi*8 ..+8]
  bf16x8 qf[4];
  {
    const u16* qp = qk + ((size_t)b * S_LEN + q0 + l31) * 2048 + h * 64 + hi * 8;
#pragma unroll
    for (int ks = 0; ks < 4; ++ks)
      qf[ks] = *reinterpret_cast<const bf16x8*>(qp + ks * 16);
  }

  // staging sources (per-lane, pre-swizzled column)
  const int swzcol = 16 * ((lane & 7) ^ (lane >> 3));
  const char* kg = (const char*)qk + ((size_t)b * S_LEN) * 4096 + 2048 + h * 128 +
                   (size_t)(lane >> 3) * 4096 + swzcol;
  const char* vg = (const char*)vt + ((size_t)bh * 64 + (lane >> 3)) * 4096 + swzcol;

#define STAGE(BUF, KT)                                                              \
  {                                                                                 \
    const char* kg_ = kg + (size_t)(KT) * 64 * 4096;                                \
    const char* vg_ = vg + (size_t)(KT) * 128;                                      \
    gload_lds16(kg_ + (size_t)(wave * 8) * 4096, &Ks[BUF][wave * 512]);             \
    gload_lds16(kg_ + (size_t)((wave + 4) * 8) * 4096, &Ks[BUF][(wave + 4) * 512]); \
    gload_lds16(vg_ + (size_t)(wave * 8) * 4096, &Vs[BUF][wave * 512]);             \
    gload_lds16(vg_ + (size_t)((wave + 4) * 8) * 4096, &Vs[BUF][(wave + 4) * 512]); \
  }

  f32x16 oT[2];  // [d-block]: O^T[d = kbd*32 + row(reg,hi)][q = l31]
#pragma unroll
  for (int kb = 0; kb < 2; ++kb)
#pragma unroll
    for (int g = 0; g < 16; ++g) oT[kb][g] = 0.f;
  float m_i = -INFINITY;
  float l_i = 0.f;

  const int rsw = (l31 & 7) << 4;  // LDS row-XOR for rows = kb*32 + l31

  STAGE(0, 0);
  __syncthreads();
  int buf = 0;

  for (int kt = 0; kt <= KTMAX; ++kt) {
    if (kt < KTMAX) STAGE(buf ^ 1, kt + 1);

    if (kt <= ktd) {
      const char* Kb = (const char*)&Ks[buf][0];
      const char* Vb = (const char*)&Vs[buf][0];
      const bool masked = (kt == ktd);

      // K fragments (A-operand): K[key = kb*32 + l31][k = ks*16 + hi*8]
      bf16x8 kf[2][4];
#pragma unroll
      for (int kb = 0; kb < 2; ++kb)
#pragma unroll
        for (int ks = 0; ks < 4; ++ks)
          kf[kb][ks] = *reinterpret_cast<const bf16x8*>(
              Kb + (kb * 32 + l31) * 128 + ((ks * 32 + hi * 16) ^ rsw));

      // S^T = K.Q^T (scores arrive already in exp2 domain: Q pre-scaled)
      f32x16 sc[2];
#pragma unroll
      for (int kb = 0; kb < 2; ++kb) {
        sc[kb] = mfma32(kf[kb][0], qf[0], f32x16{});
#pragma unroll
        for (int ks = 1; ks < 4; ++ks) sc[kb] = mfma32(kf[kb][ks], qf[ks], sc[kb]);
      }

      // V fragments (A-operand): V^T[d = kbd*32 + l31][key = t*16 + hi*8]
      bf16x8 vf[2][4];
#pragma unroll
      for (int kbd = 0; kbd < 2; ++kbd)
#pragma unroll
        for (int t = 0; t < 4; ++t)
          vf[kbd][t] = *reinterpret_cast<const bf16x8*>(
              Vb + (kbd * 32 + l31) * 128 + ((t * 32 + hi * 16) ^ rsw));

      // ---- softmax (one group) ----
      if (masked) {
#pragma unroll
        for (int kb = 0; kb < 2; ++kb)
#pragma unroll
          for (int g = 0; g < 16; ++g) {
            int key_ = kb * 32 + (g & 3) + ((g >> 2) << 3) + hi * 4;
            if (key_ > qrel) sc[kb][g] = -INFINITY;
          }
      }
      // 4-chain partial max (ILP; v_max3-friendly)
      float mxa = fmaxf(sc[0][0], sc[0][4]), mxb = fmaxf(sc[0][1], sc[0][5]);
      float mxc = fmaxf(sc[0][2], sc[0][6]), mxd = fmaxf(sc[0][3], sc[0][7]);
#pragma unroll
      for (int g = 8; g < 16; g += 4) {
        mxa = fmaxf(mxa, sc[0][g]);     mxb = fmaxf(mxb, sc[0][g + 1]);
        mxc = fmaxf(mxc, sc[0][g + 2]); mxd = fmaxf(mxd, sc[0][g + 3]);
      }
#pragma unroll
      for (int g = 0; g < 16; g += 4) {
        mxa = fmaxf(mxa, sc[1][g]);     mxb = fmaxf(mxb, sc[1][g + 1]);
        mxc = fmaxf(mxc, sc[1][g + 2]); mxd = fmaxf(mxd, sc[1][g + 3]);
      }
      float mx = fmaxf(fmaxf(mxa, mxb), fmaxf(mxc, mxd));
      mx = fmaxf(mx, __shfl_xor(mx, 32, 64));
      if (__any(mx > m_i + DEFER_THR)) {
        float mn = fmaxf(m_i, mx);
        float c = exp2_fast(m_i - mn);
        m_i = mn;
        l_i *= c;
#pragma unroll
        for (int kb = 0; kb < 2; ++kb)
#pragma unroll
          for (int g = 0; g < 16; ++g) oT[kb][g] *= c;
      }
      float rsa = 0.f, rsb = 0.f, rsc = 0.f, rsd = 0.f;
      unsigned pk_[8][2];
#pragma unroll
      for (int kb = 0; kb < 2; ++kb)
#pragma unroll
        for (int s = 0; s < 4; ++s) {
          float p0 = exp2_fast(sc[kb][s * 4 + 0] - m_i);
          float p1 = exp2_fast(sc[kb][s * 4 + 1] - m_i);
          float p2 = exp2_fast(sc[kb][s * 4 + 2] - m_i);
          float p3 = exp2_fast(sc[kb][s * 4 + 3] - m_i);
          rsa += p0; rsb += p1; rsc += p2; rsd += p3;
          pk_[kb * 4 + s][0] = cvtpk_bf16(p0, p1);
          pk_[kb * 4 + s][1] = cvtpk_bf16(p2, p3);
        }
      float rs = (rsa + rsb) + (rsc + rsd);
      rs += __shfl_xor(rs, 32, 64);
      l_i += rs;

      // P fragments via permlane32_swap
      bf16x8 pfr[4];
#pragma unroll
      for (int t = 0; t < 4; ++t) {
        unsigned a0 = pk_[2 * t][0], b0 = pk_[2 * t + 1][0];
        unsigned a1 = pk_[2 * t][1], b1 = pk_[2 * t + 1][1];
        plswap(a0, b0);
        plswap(a1, b1);
        unsigned fr[4] = {a0, a1, b0, b1};
        pfr[t] = *reinterpret_cast<const bf16x8*>(&fr[0]);
      }

      // O^T += V^T.P^T
#pragma unroll
      for (int t = 0; t < 4; ++t) {
        oT[0] = mfma32(vf[0][t], pfr[t], oT[0]);
        oT[1] = mfma32(vf[1][t], pfr[t], oT[1]);
      }
    }

    __syncthreads();
    buf ^= 1;
  }
#undef STAGE

  // epilogue: out row = q = q0 + l31; d = kbd*32 + (g&3) + 8*(g>>2) + 4*hi
  {
    float inv = 1.f / l_i;
    u16* orow = ao + ((size_t)b * S_LEN + q0 + l31) * DMODEL + h * 64 + hi * 4;
#pragma unroll
    for (int kbd = 0; kbd < 2; ++kbd)
#pragma unroll
      for (int s = 0; s < 4; ++s) {
        unsigned w0 = cvtpk_bf16(oT[kbd][s * 4 + 0] * inv, oT[kbd][s * 4 + 1] * inv);
        unsigned w1 = cvtpk_bf16(oT[kbd][s * 4 + 2] * inv, oT[kbd][s * 4 + 3] * inv);
        *reinterpret_cast<unsigned*>(orow + kbd * 32 + s * 8) = w0;
        *reinterpret_cast<unsigned*>(orow + kbd * 32 + s * 8 + 2) = w1;
      }
  }
}

// ---------------- launch ----------------
extern "C" void kernel_launch(void* const* d_in, const int* in_sizes, int n_in,
                              void* d_out, int out_size, void* d_ws, size_t ws_size,
                              hipStream_t stream) {
  const float* x = (const float*)d_in[0];
  const float* wqkv = (const float*)d_in[1];
  const float* bqkv = (const float*)d_in[2];
  const float* wproj = (const float*)d_in[3];
  const float* bproj = (const float*)d_in[4];
  float* out = (float*)d_out;

  char* ws = (char*)d_ws;
  u16* Xb     = (u16*)(ws);                       // [8192][1024] bf16, 16 MiB
  u16* Wqkvt  = (u16*)(ws + (size_t)16777216);    // [3072][1024] bf16,  6 MiB
  u16* Wprojt = (u16*)(ws + (size_t)23068672);    // [1024][1024] bf16,  2 MiB
  u16* QKb    = (u16*)(ws + (size_t)25165824);    // [8192][2048] bf16, 32 MiB
  u16* Vt     = (u16*)(ws + (size_t)58720256);    // [64*64][2048] bf16, 16 MiB
  u16* AOb    = (u16*)(ws + (size_t)75497472);    // [8192][1024] bf16, 16 MiB

  k_f32_to_bf16<<<MROWS * DMODEL / 4 / 256, 256, 0, stream>>>(x, Xb, MROWS * DMODEL);
  k_transpose_to_bf16<<<dim3(3072 / 32, 1024 / 32), 256, 0, stream>>>(wqkv, Wqkvt, 1024, 3072);
  k_transpose_to_bf16<<<dim3(1024 / 32, 1024 / 32), 256, 0, stream>>>(wproj, Wprojt, 1024, 1024);

  // qkv GEMM: Q (pre-scaled), K -> QKb (row stride 2048); V -> Vt transposed
  k_gemm8<2><<<dim3(MROWS / 256, 3072 / 128), 512, 0, stream>>>(
      Xb, Wqkvt, bqkv, QKb, nullptr, Vt, 3072, 1024);

  k_attn6<<<dim3(1024), 256, 0, stream>>>(QKb, Vt, AOb);

  k_gemm8<1><<<dim3(MROWS / 256, DMODEL / 128), 512, 0, stream>>>(
      AOb, Wprojt, bproj, nullptr, out, nullptr, DMODEL, 1024);
}

// Round 8
// 186.403 us; speedup vs baseline: 1.0277x; 1.0277x over previous
//
#include <hip/hip_runtime.h>

// CausalSelfAttention: B=4, S=2048, D=1024, H=16, HS=64
// bf16 MFMA everywhere, fp32 accumulate.
// GEMMs: 256x128 tile, 8 waves, k-split half-tile pipeline (counted vmcnt).
// attn v7: 32x32 MFMA swapped operands; 8-wave blocks (512 thr) sharing one
// K/V double-buffer; wave owns 32 rows; 2 blocks/CU -> 4 waves/SIMD;
// CU-balanced tile pairing; pre-scaled Q (exp2 domain); in-register P.

typedef unsigned short u16;
typedef short bf16x8 __attribute__((ext_vector_type(8)));
typedef unsigned short u16x8 __attribute__((ext_vector_type(8)));
typedef float f32x4 __attribute__((ext_vector_type(4)));
typedef float f32x16 __attribute__((ext_vector_type(16)));

#define S_LEN 2048
#define DMODEL 1024
#define NHEAD 16
#define MROWS 8192  // B*S

// 0.25 (1/sqrt(H)) * log2(e)
#define SCALE_LOG2E 0.36067376022224085f
#define DEFER_THR 8.0f

__device__ __forceinline__ u16 f2bf(float f) {
  union { float f; unsigned u; } c; c.f = f;
  unsigned u = c.u;
  u += 0x7fffu + ((u >> 16) & 1u);  // RNE
  return (u16)(u >> 16);
}

__device__ __forceinline__ float exp2_fast(float x) {
  float r; asm("v_exp_f32 %0, %1" : "=v"(r) : "v"(x)); return r;
}

__device__ __forceinline__ unsigned cvtpk_bf16(float a, float b) {
  unsigned r;
  asm("v_cvt_pk_bf16_f32 %0, %1, %2" : "=v"(r) : "v"(a), "v"(b));
  return r;
}

// v_permlane32_swap_b32: a' = {a_lo, b_lo}, b' = {a_hi, b_hi}
__device__ __forceinline__ void plswap(unsigned& a, unsigned& b) {
  asm("v_permlane32_swap_b32 %0, %1" : "+v"(a), "+v"(b));
}

__device__ __forceinline__ f32x4 mfma16(bf16x8 a, bf16x8 b, f32x4 c) {
  return __builtin_amdgcn_mfma_f32_16x16x32_bf16(a, b, c, 0, 0, 0);
}

__device__ __forceinline__ f32x16 mfma32(bf16x8 a, bf16x8 b, f32x16 c) {
  return __builtin_amdgcn_mfma_f32_32x32x16_bf16(a, b, c, 0, 0, 0);
}

__device__ __forceinline__ void gload_lds16(const void* g, void* l) {
  __builtin_amdgcn_global_load_lds((__attribute__((address_space(1))) void*)g,
                                   (__attribute__((address_space(3))) void*)l,
                                   16, 0, 0);
}

// ---------------- conversion kernels ----------------
__global__ void k_f32_to_bf16(const float* __restrict__ in, u16* __restrict__ out, int n) {
  int i = (blockIdx.x * 256 + threadIdx.x) * 4;
  if (i < n) {
    float4 v = *reinterpret_cast<const float4*>(in + i);
    ushort4 o;
    o.x = f2bf(v.x); o.y = f2bf(v.y); o.z = f2bf(v.z); o.w = f2bf(v.w);
    *reinterpret_cast<ushort4*>(out + i) = o;
  }
}

// w[K][N] fp32 -> wt[N][K] bf16
__global__ void k_transpose_to_bf16(const float* __restrict__ in, u16* __restrict__ out,
                                    int K, int N) {
  __shared__ float t[32][33];
  int n0 = blockIdx.x * 32, k0 = blockIdx.y * 32;
  int tx = threadIdx.x & 31, ty = threadIdx.x >> 5;  // 32 x 8
#pragma unroll
  for (int i = 0; i < 32; i += 8)
    t[ty + i][tx] = in[(size_t)(k0 + ty + i) * N + n0 + tx];
  __syncthreads();
#pragma unroll
  for (int i = 0; i < 32; i += 8)
    out[(size_t)(n0 + ty + i) * K + k0 + tx] = f2bf(t[tx][ty + i]);
}

// ---------------- GEMM v2: C[M][N] = A[M][K] * Bt[N][K]^T + bias ----------------
// 256x128 tile, 512 threads (8 waves: 4 wr x 2 wc), BK=64 as two k-halves.
// MODE 1: fp32 out.  MODE 2: qkv-split (col<1024 -> Q pre-scaled by SCALE_LOG2E;
// col<2048 -> qk bf16; else V -> vt^T).
template <int MODE>
__global__ __launch_bounds__(512, 1) void k_gemm8(const u16* __restrict__ A,
                                                  const u16* __restrict__ Bt,
                                                  const float* __restrict__ bias,
                                                  u16* __restrict__ outb,
                                                  float* __restrict__ outf,
                                                  u16* __restrict__ vtout,
                                                  int N, int K) {
  __shared__ u16 As[2][2][256 * 32];  // [buf][khalf][row][32 k-elems], 64B rows
  __shared__ u16 Bs[2][2][128 * 32];

  const int tid = threadIdx.x;
  const int lane = tid & 63, wave = tid >> 6;
  const int wr = wave >> 1, wc = wave & 1;
  const int lr = lane & 15, lk = lane >> 4;
  const int m0 = blockIdx.x * 256, n0 = blockIdx.y * 128;
  const size_t Kb = (size_t)K * 2;  // row stride bytes

  const int csw = ((tid & 3) ^ ((tid >> 3) & 3)) * 16;
  const char* Asrc0 = (const char*)A + (size_t)(m0 + (tid >> 2)) * Kb + csw;
  const char* Asrc1 = Asrc0 + 128 * Kb;
  const char* Bsrc0 = (const char*)Bt + (size_t)(n0 + (tid >> 2)) * Kb + csw;

#define STAGE_KH(BUFX, KH, T)                                                  \
  {                                                                            \
    const size_t ko_ = (size_t)(T) * 128 + (KH) * 64;                          \
    gload_lds16(Asrc0 + ko_, &As[BUFX][KH][(size_t)tid * 8]);                  \
    gload_lds16(Asrc1 + ko_, &As[BUFX][KH][((size_t)tid + 512) * 8]);          \
    gload_lds16(Bsrc0 + ko_, &Bs[BUFX][KH][(size_t)tid * 8]);                  \
  }

  f32x4 zero4 = {0.f, 0.f, 0.f, 0.f};
  f32x4 acc[4][4];
#pragma unroll
  for (int m = 0; m < 4; ++m)
#pragma unroll
    for (int n = 0; n < 4; ++n) acc[m][n] = zero4;

  const int slotsw = (lr >> 1) & 3;  // read-side swizzle: chunk = lk ^ slotsw

#define PHASE(BUFX, KH, T, DOSTAGE, VMZERO)                                    \
  {                                                                            \
    if (VMZERO) asm volatile("s_waitcnt vmcnt(0)" ::: "memory");               \
    else        asm volatile("s_waitcnt vmcnt(3)" ::: "memory");               \
    __builtin_amdgcn_s_barrier();                                              \
    __builtin_amdgcn_sched_barrier(0);                                         \
    bf16x8 af[4], bfr[4];                                                      \
    _Pragma("unroll") for (int m = 0; m < 4; ++m)                              \
        af[m] = *reinterpret_cast<const bf16x8*>(                              \
            &As[BUFX][KH][(wr * 64 + m * 16 + lr) * 32 + ((lk ^ slotsw) * 8)]);\
    _Pragma("unroll") for (int n = 0; n < 4; ++n)                              \
        bfr[n] = *reinterpret_cast<const bf16x8*>(                             \
            &Bs[BUFX][KH][(wc * 64 + n * 16 + lr) * 32 + ((lk ^ slotsw) * 8)]);\
    if (DOSTAGE) STAGE_KH((BUFX) ^ 1, KH, (T) + 1);                            \
    __builtin_amdgcn_sched_barrier(0);                                         \
    __builtin_amdgcn_s_setprio(1);                                             \
    _Pragma("unroll") for (int m = 0; m < 4; ++m)                              \
        _Pragma("unroll") for (int n = 0; n < 4; ++n)                          \
            acc[m][n] = mfma16(af[m], bfr[n], acc[m][n]);                      \
    __builtin_amdgcn_s_setprio(0);                                             \
  }

  const int nkt = K >> 6;  // 16
  STAGE_KH(0, 0, 0);
  STAGE_KH(0, 1, 0);

  for (int t = 0; t < nkt - 1; ++t) {
    const int buf = t & 1;
    PHASE(buf, 0, t, 1, 0);
    PHASE(buf, 1, t, 1, 0);
  }
  {
    const int buf = (nkt - 1) & 1;
    PHASE(buf, 0, nkt - 1, 0, 0);
    PHASE(buf, 1, nkt - 1, 0, 1);
  }
#undef PHASE
#undef STAGE_KH

  // epilogue
#pragma unroll
  for (int n = 0; n < 4; ++n) {
    int col = n0 + wc * 64 + n * 16 + lr;
    float bv = bias[col];
#pragma unroll
    for (int m = 0; m < 4; ++m) {
      int rowb = m0 + wr * 64 + m * 16 + lk * 4;
      if (MODE == 1) {
#pragma unroll
        for (int r = 0; r < 4; ++r)
          outf[(size_t)(rowb + r) * N + col] = acc[m][n][r] + bv;
      } else {
        if (col < 2048) {
          const float qs = (col < 1024) ? SCALE_LOG2E : 1.0f;  // pre-scale Q
#pragma unroll
          for (int r = 0; r < 4; ++r)
            outb[(size_t)(rowb + r) * 2048 + col] = f2bf((acc[m][n][r] + bv) * qs);
        } else {
          int hh = (col >> 6) & 15, dd = col & 63;
          int bb = rowb >> 11, ss = rowb & 2047;
          ushort4 o;
          o.x = f2bf(acc[m][n][0] + bv);
          o.y = f2bf(acc[m][n][1] + bv);
          o.z = f2bf(acc[m][n][2] + bv);
          o.w = f2bf(acc[m][n][3] + bv);
          *reinterpret_cast<ushort4*>(
              vtout + ((size_t)(bb * 16 + hh) * 64 + dd) * 2048 + ss) = o;
        }
      }
    }
  }
}

// ---------------- flash attention v7 (32x32 MFMA, 8-wave block) ----------------
// grid 512: bh = gid&63, tq = gid>>6 -> tile t via pairing perm (t + t' = 7 per
// CU cohort {g, g+256}). Block = 8 waves (512 thr) over 256 q-rows; ONE shared
// K/V dbuf serves all waves (staging union). Wave owns 32 rows.
__global__ __launch_bounds__(512, 4) void k_attn7(const u16* __restrict__ qk,
                                                  const u16* __restrict__ vt,
                                                  u16* __restrict__ ao) {
  __shared__ u16 Ks[2][4096];   // [key 0..63][k 0..63], 128B rows, XOR-swizzled
  __shared__ u16 Vs[2][4096];   // [d 0..63][key 0..63], swizzled

  const int tid = threadIdx.x;
  const int lane = tid & 63, wave = tid >> 6;
  const int l31 = lane & 31, hi = lane >> 5;
  const int gid = blockIdx.x;
  const int bh = gid & 63;
  const int tq = gid >> 6;
  const int t = (tq < 4) ? tq : 11 - tq;  // cohort {g,g+256}: t+t' = 7
  const int b = bh >> 4, h = bh & 15;

  const int q0 = t * 256 + wave * 32;
  const int ktd = (q0 + 31) >> 6;        // wave's diagonal tile = 4t + (wave>>1)
  const int KTMAX = 4 * t + 3;           // block-level last tile
  const int qrel = q0 + l31 - ktd * 64;  // mask: key_in_tile > qrel

  // Q fragments (B-operand): lane holds Q[q = l31][k = ks*16 + hi*8 ..+8]
  bf16x8 qf[4];
  {
    const u16* qp = qk + ((size_t)b * S_LEN + q0 + l31) * 2048 + h * 64 + hi * 8;
#pragma unroll
    for (int ks = 0; ks < 4; ++ks)
      qf[ks] = *reinterpret_cast<const bf16x8*>(qp + ks * 16);
  }

  // staging: wave w stages K rows [8w,8w+8) and V rows [8w,8w+8) of the tile
  const int swzcol = 16 * ((lane & 7) ^ (lane >> 3));
  const char* kg = (const char*)qk + ((size_t)b * S_LEN) * 4096 + 2048 + h * 128 +
                   (size_t)(wave * 8 + (lane >> 3)) * 4096 + swzcol;
  const char* vg = (const char*)vt +
                   ((size_t)bh * 64 + wave * 8 + (lane >> 3)) * 4096 + swzcol;

#define STAGE(BUF, KT)                                                   \
  {                                                                      \
    gload_lds16(kg + (size_t)(KT) * 64 * 4096, &Ks[BUF][wave * 512]);    \
    gload_lds16(vg + (size_t)(KT) * 128, &Vs[BUF][wave * 512]);          \
  }

  f32x16 oT[2];  // [d-block]: O^T[d = kbd*32 + (g&3)+8*(g>>2)+4*hi][q = l31]
#pragma unroll
  for (int kb = 0; kb < 2; ++kb)
#pragma unroll
    for (int g = 0; g < 16; ++g) oT[kb][g] = 0.f;
  float m_i = -INFINITY;
  float l_i = 0.f;

  const int rsw = (l31 & 7) << 4;  // LDS row-XOR for rows = kb*32 + l31

  STAGE(0, 0);
  __syncthreads();
  int buf = 0;

  for (int kt = 0; kt <= KTMAX; ++kt) {
    if (kt < KTMAX) STAGE(buf ^ 1, kt + 1);

    if (kt <= ktd) {
      const char* Kb = (const char*)&Ks[buf][0];
      const char* Vb = (const char*)&Vs[buf][0];
      const bool masked = (kt == ktd);

      // K fragments (A-operand): K[key = kb*32 + l31][k = ks*16 + hi*8]
      bf16x8 kf[2][4];
#pragma unroll
      for (int kb = 0; kb < 2; ++kb)
#pragma unroll
        for (int ks = 0; ks < 4; ++ks)
          kf[kb][ks] = *reinterpret_cast<const bf16x8*>(
              Kb + (kb * 32 + l31) * 128 + ((ks * 32 + hi * 16) ^ rsw));

      // S^T = K.Q^T (scores already in exp2 domain: Q pre-scaled)
      f32x16 sc[2];
#pragma unroll
      for (int kb = 0; kb < 2; ++kb) {
        sc[kb] = mfma32(kf[kb][0], qf[0], f32x16{});
#pragma unroll
        for (int ks = 1; ks < 4; ++ks) sc[kb] = mfma32(kf[kb][ks], qf[ks], sc[kb]);
      }

      // V fragments (A-operand): V^T[d = kbd*32 + l31][key = t*16 + hi*8]
      bf16x8 vf[2][4];
#pragma unroll
      for (int kbd = 0; kbd < 2; ++kbd)
#pragma unroll
        for (int tt = 0; tt < 4; ++tt)
          vf[kbd][tt] = *reinterpret_cast<const bf16x8*>(
              Vb + (kbd * 32 + l31) * 128 + ((tt * 32 + hi * 16) ^ rsw));

      // ---- softmax ----
      if (masked) {
#pragma unroll
        for (int kb = 0; kb < 2; ++kb)
#pragma unroll
          for (int g = 0; g < 16; ++g) {
            int key_ = kb * 32 + (g & 3) + ((g >> 2) << 3) + hi * 4;
            if (key_ > qrel) sc[kb][g] = -INFINITY;
          }
      }
      float mxa = fmaxf(sc[0][0], sc[0][4]), mxb = fmaxf(sc[0][1], sc[0][5]);
      float mxc = fmaxf(sc[0][2], sc[0][6]), mxd = fmaxf(sc[0][3], sc[0][7]);
#pragma unroll
      for (int g = 8; g < 16; g += 4) {
        mxa = fmaxf(mxa, sc[0][g]);     mxb = fmaxf(mxb, sc[0][g + 1]);
        mxc = fmaxf(mxc, sc[0][g + 2]); mxd = fmaxf(mxd, sc[0][g + 3]);
      }
#pragma unroll
      for (int g = 0; g < 16; g += 4) {
        mxa = fmaxf(mxa, sc[1][g]);     mxb = fmaxf(mxb, sc[1][g + 1]);
        mxc = fmaxf(mxc, sc[1][g + 2]); mxd = fmaxf(mxd, sc[1][g + 3]);
      }
      float mx = fmaxf(fmaxf(mxa, mxb), fmaxf(mxc, mxd));
      mx = fmaxf(mx, __shfl_xor(mx, 32, 64));
      if (__any(mx > m_i + DEFER_THR)) {
        float mn = fmaxf(m_i, mx);
        float c = exp2_fast(m_i - mn);
        m_i = mn;
        l_i *= c;
#pragma unroll
        for (int kb = 0; kb < 2; ++kb)
#pragma unroll
          for (int g = 0; g < 16; ++g) oT[kb][g] *= c;
      }
      float rsa = 0.f, rsb = 0.f, rsc = 0.f, rsd = 0.f;
      unsigned pk_[8][2];
#pragma unroll
      for (int kb = 0; kb < 2; ++kb)
#pragma unroll
        for (int s = 0; s < 4; ++s) {
          float p0 = exp2_fast(sc[kb][s * 4 + 0] - m_i);
          float p1 = exp2_fast(sc[kb][s * 4 + 1] - m_i);
          float p2 = exp2_fast(sc[kb][s * 4 + 2] - m_i);
          float p3 = exp2_fast(sc[kb][s * 4 + 3] - m_i);
          rsa += p0; rsb += p1; rsc += p2; rsd += p3;
          pk_[kb * 4 + s][0] = cvtpk_bf16(p0, p1);
          pk_[kb * 4 + s][1] = cvtpk_bf16(p2, p3);
        }
      float rs = (rsa + rsb) + (rsc + rsd);
      rs += __shfl_xor(rs, 32, 64);
      l_i += rs;

      // P fragments via permlane32_swap
      bf16x8 pfr[4];
#pragma unroll
      for (int tt = 0; tt < 4; ++tt) {
        unsigned a0 = pk_[2 * tt][0], b0 = pk_[2 * tt + 1][0];
        unsigned a1 = pk_[2 * tt][1], b1 = pk_[2 * tt + 1][1];
        plswap(a0, b0);
        plswap(a1, b1);
        unsigned fr[4] = {a0, a1, b0, b1};
        pfr[tt] = *reinterpret_cast<const bf16x8*>(&fr[0]);
      }

      // O^T += V^T.P^T
#pragma unroll
      for (int tt = 0; tt < 4; ++tt) {
        oT[0] = mfma32(vf[0][tt], pfr[tt], oT[0]);
        oT[1] = mfma32(vf[1][tt], pfr[tt], oT[1]);
      }
    }

    __syncthreads();
    buf ^= 1;
  }
#undef STAGE

  // epilogue: out row = q = q0 + l31; d = kbd*32 + (g&3)*?  (layout as attn6)
  {
    float inv = 1.f / l_i;
    u16* orow = ao + ((size_t)b * S_LEN + q0 + l31) * DMODEL + h * 64 + hi * 4;
#pragma unroll
    for (int kbd = 0; kbd < 2; ++kbd)
#pragma unroll
      for (int s = 0; s < 4; ++s) {
        unsigned w0 = cvtpk_bf16(oT[kbd][s * 4 + 0] * inv, oT[kbd][s * 4 + 1] * inv);
        unsigned w1 = cvtpk_bf16(oT[kbd][s * 4 + 2] * inv, oT[kbd][s * 4 + 3] * inv);
        *reinterpret_cast<unsigned*>(orow + kbd * 32 + s * 8) = w0;
        *reinterpret_cast<unsigned*>(orow + kbd * 32 + s * 8 + 2) = w1;
      }
  }
}

// ---------------- launch ----------------
extern "C" void kernel_launch(void* const* d_in, const int* in_sizes, int n_in,
                              void* d_out, int out_size, void* d_ws, size_t ws_size,
                              hipStream_t stream) {
  const float* x = (const float*)d_in[0];
  const float* wqkv = (const float*)d_in[1];
  const float* bqkv = (const float*)d_in[2];
  const float* wproj = (const float*)d_in[3];
  const float* bproj = (const float*)d_in[4];
  float* out = (float*)d_out;

  char* ws = (char*)d_ws;
  u16* Xb     = (u16*)(ws);                       // [8192][1024] bf16, 16 MiB
  u16* Wqkvt  = (u16*)(ws + (size_t)16777216);    // [3072][1024] bf16,  6 MiB
  u16* Wprojt = (u16*)(ws + (size_t)23068672);    // [1024][1024] bf16,  2 MiB
  u16* QKb    = (u16*)(ws + (size_t)25165824);    // [8192][2048] bf16, 32 MiB
  u16* Vt     = (u16*)(ws + (size_t)58720256);    // [64*64][2048] bf16, 16 MiB
  u16* AOb    = (u16*)(ws + (size_t)75497472);    // [8192][1024] bf16, 16 MiB

  k_f32_to_bf16<<<MROWS * DMODEL / 4 / 256, 256, 0, stream>>>(x, Xb, MROWS * DMODEL);
  k_transpose_to_bf16<<<dim3(3072 / 32, 1024 / 32), 256, 0, stream>>>(wqkv, Wqkvt, 1024, 3072);
  k_transpose_to_bf16<<<dim3(1024 / 32, 1024 / 32), 256, 0, stream>>>(wproj, Wprojt, 1024, 1024);

  // qkv GEMM: Q (pre-scaled), K -> QKb (row stride 2048); V -> Vt transposed
  k_gemm8<2><<<dim3(MROWS / 256, 3072 / 128), 512, 0, stream>>>(
      Xb, Wqkvt, bqkv, QKb, nullptr, Vt, 3072, 1024);

  k_attn7<<<dim3(512), 512, 0, stream>>>(QKb, Vt, AOb);

  k_gemm8<1><<<dim3(MROWS / 256, DMODEL / 128), 512, 0, stream>>>(
      AOb, Wprojt, bproj, nullptr, out, nullptr, DMODEL, 1024);
}